// Round 1
// baseline (2648.642 us; speedup 1.0000x reference)
//
#include <hip/hip_runtime.h>
#include <math.h>

#define NN 100000
#define HW 100     // hidden width
#define NHID 8

// ---------------- init ----------------
__global__ void k_init(int* __restrict__ intdeg, int* __restrict__ cursor,
                       float* __restrict__ accums, int n) {
    int i = blockIdx.x * blockDim.x + threadIdx.x;
    int st = gridDim.x * blockDim.x;
    for (; i < n; i += st) { intdeg[i] = 0; cursor[i] = 0; }
    if (blockIdx.x == 0 && threadIdx.x == 0) { accums[0] = 0.f; accums[1] = 0.f; }
}

// ---------------- degree count ----------------
__global__ void k_deg(const int* __restrict__ dst, int E, int* __restrict__ intdeg) {
    int i = blockIdx.x * blockDim.x + threadIdx.x;
    int st = gridDim.x * blockDim.x;
    for (; i < E; i += st) atomicAdd(&intdeg[dst[i]], 1);
}

// ---------------- dinv ----------------
__global__ void k_dinv(const int* __restrict__ intdeg, float* __restrict__ dinv, int n) {
    int i = blockIdx.x * blockDim.x + threadIdx.x;
    if (i < n) dinv[i] = rsqrtf((float)intdeg[i] + 1.0f);   // +1 self loop
}

// ---------------- 2-level exclusive scan of intdeg -> offsets ----------------
__global__ void k_scan1(const int* __restrict__ deg, int n, int* __restrict__ blockTotals) {
    __shared__ int s[256];
    int base = blockIdx.x * 1024 + threadIdx.x * 4;
    int tsum = 0;
    #pragma unroll
    for (int j = 0; j < 4; ++j) { int idx = base + j; tsum += (idx < n) ? deg[idx] : 0; }
    s[threadIdx.x] = tsum; __syncthreads();
    for (int off = 128; off; off >>= 1) {
        if (threadIdx.x < off) s[threadIdx.x] += s[threadIdx.x + off];
        __syncthreads();
    }
    if (threadIdx.x == 0) blockTotals[blockIdx.x] = s[0];
}

__global__ void k_scan2(const int* __restrict__ blockTotals, int nb,
                        int* __restrict__ blockOffsets, int* __restrict__ offsets, int n) {
    if (blockIdx.x == 0 && threadIdx.x == 0) {
        int run = 0;
        for (int i = 0; i < nb; ++i) { blockOffsets[i] = run; run += blockTotals[i]; }
        offsets[n] = run;
    }
}

__global__ void k_scan3(const int* __restrict__ deg, int n,
                        const int* __restrict__ blockOffsets, int* __restrict__ offsets) {
    __shared__ int s[256];
    int tid = threadIdx.x;
    int base = blockIdx.x * 1024 + tid * 4;
    int v[4]; int tsum = 0;
    #pragma unroll
    for (int j = 0; j < 4; ++j) { int idx = base + j; v[j] = (idx < n) ? deg[idx] : 0; tsum += v[j]; }
    s[tid] = tsum; __syncthreads();
    for (int off = 1; off < 256; off <<= 1) {
        int x = (tid >= off) ? s[tid - off] : 0;
        __syncthreads();
        s[tid] += x;
        __syncthreads();
    }
    int run = blockOffsets[blockIdx.x] + (s[tid] - tsum);
    #pragma unroll
    for (int j = 0; j < 4; ++j) { int idx = base + j; if (idx < n) offsets[idx] = run; run += v[j]; }
}

// ---------------- CSR fill ----------------
__global__ void k_fill(const int* __restrict__ src, const int* __restrict__ dst, int E,
                       const int* __restrict__ offsets, int* __restrict__ cursor,
                       const float* __restrict__ dinv,
                       int* __restrict__ csr_src, float* __restrict__ csr_w) {
    int i = blockIdx.x * blockDim.x + threadIdx.x;
    int st = gridDim.x * blockDim.x;
    for (; i < E; i += st) {
        int d = dst[i], s = src[i];
        int pos = offsets[d] + atomicAdd(&cursor[d], 1);
        csr_src[pos] = s;
        csr_w[pos] = dinv[s] * dinv[d];
    }
}

// ---------------- fp32 GEMM: out[n,H] = h[n,F] @ W[F,H] (+bias) ----------------
// block = 256 threads, 32 rows/block; col threads (tid&31)*4, top 7 idle (c0>=100)
template<int F>
__global__ __launch_bounds__(256) void k_gemm(const float* __restrict__ h,
                                              const float* __restrict__ W,
                                              const float* __restrict__ bias,
                                              float* __restrict__ out, int n) {
    __shared__ float Ws[F * HW];
    int tid = threadIdx.x;
    for (int i = tid; i < F * HW; i += 256) Ws[i] = W[i];
    __syncthreads();
    int c0 = (tid & 31) * 4;
    if (c0 >= HW) return;          // no further barriers below
    int r0 = blockIdx.x * 32 + (tid >> 5) * 4;
    float acc[4][4] = {};
    const float* h0 = h + (size_t)r0 * F;
    for (int k = 0; k < F; ++k) {
        float4 w = *reinterpret_cast<const float4*>(&Ws[k * HW + c0]);
        #pragma unroll
        for (int r = 0; r < 4; ++r) {
            float hv = h0[(size_t)r * F + k];
            acc[r][0] = fmaf(hv, w.x, acc[r][0]);
            acc[r][1] = fmaf(hv, w.y, acc[r][1]);
            acc[r][2] = fmaf(hv, w.z, acc[r][2]);
            acc[r][3] = fmaf(hv, w.w, acc[r][3]);
        }
    }
    float4 bv = make_float4(0.f, 0.f, 0.f, 0.f);
    if (bias) bv = *reinterpret_cast<const float4*>(&bias[c0]);
    #pragma unroll
    for (int r = 0; r < 4; ++r) {
        int row = r0 + r;
        if (row < n) {
            float4 o = make_float4(acc[r][0] + bv.x, acc[r][1] + bv.y,
                                   acc[r][2] + bv.z, acc[r][3] + bv.w);
            *reinterpret_cast<float4*>(&out[(size_t)row * HW + c0]) = o;
        }
    }
}

// ---------------- aggregation: out[i,:] = sum_e w_e * t[src_e,:] + dinv_i^2 * t[i,:] + bias ----
__global__ __launch_bounds__(256) void k_agg(const float* __restrict__ t,
                                             const int* __restrict__ csr_src,
                                             const float* __restrict__ csr_w,
                                             const int* __restrict__ offsets,
                                             const float* __restrict__ dinv,
                                             const float* __restrict__ bias,
                                             float* __restrict__ out, int n) {
    int node = blockIdx.x * 4 + (threadIdx.x >> 6);
    int lane = threadIdx.x & 63;
    if (node >= n) return;
    int beg = offsets[node], end = offsets[node + 1];
    float di = dinv[node];
    float sw = di * di;
    const float* trow = t + (size_t)node * HW;
    float a0 = trow[lane] * sw;
    float a1 = (lane < HW - 64) ? trow[64 + lane] * sw : 0.f;
    for (int e = beg; e < end; ++e) {
        int s = csr_src[e];
        float w = csr_w[e];
        const float* tr = t + (size_t)s * HW;
        a0 = fmaf(w, tr[lane], a0);
        if (lane < HW - 64) a1 = fmaf(w, tr[64 + lane], a1);
    }
    out[(size_t)node * HW + lane] = a0 + bias[lane];
    if (lane < HW - 64) out[(size_t)node * HW + 64 + lane] = a1 + bias[64 + lane];
}

// ---------------- pos = sum(labels) ----------------
__global__ void k_pos(const float* __restrict__ labels, int n, float* __restrict__ accums) {
    __shared__ float s[256];
    float v = 0.f;
    for (int i = blockIdx.x * blockDim.x + threadIdx.x; i < n; i += gridDim.x * blockDim.x)
        v += labels[i];
    s[threadIdx.x] = v; __syncthreads();
    for (int off = 128; off; off >>= 1) {
        if (threadIdx.x < off) s[threadIdx.x] += s[threadIdx.x + off];
        __syncthreads();
    }
    if (threadIdx.x == 0) atomicAdd(&accums[0], s[0]);
}

// ---------------- fc2 + sigmoid + weighted BCE partials ----------------
__global__ __launch_bounds__(256) void k_fc2_loss(const float* __restrict__ g,
                                                  const float* __restrict__ w2,
                                                  const float* __restrict__ b2,
                                                  const float* __restrict__ labels,
                                                  const float* __restrict__ accums,
                                                  float* __restrict__ out_p,
                                                  float* __restrict__ loss_accum, int n) {
    __shared__ float ls[4];
    int wid = threadIdx.x >> 6, lane = threadIdx.x & 63;
    int node = blockIdx.x * 4 + wid;
    float v = 0.f;
    if (node < n) {
        const float* gr = g + (size_t)node * HW;
        v = gr[lane] * w2[lane];
        if (lane < HW - 64) v += gr[64 + lane] * w2[64 + lane];
    }
    #pragma unroll
    for (int off = 32; off; off >>= 1) v += __shfl_down(v, off);
    float nodeLoss = 0.f;
    if (lane == 0) {
        if (node < n) {
            float logit = v + b2[0];
            float p = 1.f / (1.f + expf(-logit));
            out_p[node] = p;
            float pc = fminf(fmaxf(p, 1e-7f), 1.f - 1e-7f);
            float l = labels[node];
            float pos = accums[0];
            float w = ((float)n - pos) / pos * l + 1.f;
            nodeLoss = w * (-(l * logf(pc) + (1.f - l) * logf(1.f - pc)));
        }
        ls[wid] = nodeLoss;
    }
    __syncthreads();
    if (threadIdx.x == 0) atomicAdd(loss_accum, ls[0] + ls[1] + ls[2] + ls[3]);
}

__global__ void k_final(const float* __restrict__ accums, float* __restrict__ out0, int n) {
    if (blockIdx.x == 0 && threadIdx.x == 0) out0[0] = accums[1] / (float)n;
}

// ---------------- launch ----------------
extern "C" void kernel_launch(void* const* d_in, const int* in_sizes, int n_in,
                              void* d_out, int out_size, void* d_ws, size_t ws_size,
                              hipStream_t stream) {
    const float* x      = (const float*)d_in[0];
    const int*   edge   = (const int*)d_in[1];
    const float* labels = (const float*)d_in[2];
    const float* W1     = (const float*)d_in[3];
    const float* b1     = (const float*)d_in[4];
    const float* Wh     = (const float*)d_in[5];
    const float* bh     = (const float*)d_in[6];
    const float* fc1W   = (const float*)d_in[7];
    const float* fc1b   = (const float*)d_in[8];
    const float* fc2W   = (const float*)d_in[9];
    const float* fc2b   = (const float*)d_in[10];

    const int N = in_sizes[0] / 128;   // 100000
    const int E = in_sizes[1] / 2;     // 1600000
    const int* srcIdx = edge;
    const int* dstIdx = edge + E;

    // workspace carve (512B aligned)
    size_t o = 0;
    auto carve = [&](size_t bytes) {
        void* p = (char*)d_ws + o;
        o += (bytes + 511) & ~(size_t)511;
        return p;
    };
    float* dinv        = (float*)carve((size_t)N * 4);
    int*   offsets     = (int*)  carve((size_t)(N + 1) * 4);
    int*   intdeg      = (int*)  carve((size_t)N * 4);
    int*   cursor      = (int*)  carve((size_t)N * 4);
    int*   blockTotals = (int*)  carve(256 * 4);
    int*   blockOffs   = (int*)  carve(256 * 4);
    float* accums      = (float*)carve(2 * 4);
    int*   csr_src     = (int*)  carve((size_t)E * 4);
    float* csr_w       = (float*)carve((size_t)E * 4);
    float* tbuf        = (float*)carve((size_t)N * HW * 4);
    float* hbuf        = (float*)carve((size_t)N * HW * 4);
    (void)ws_size; (void)n_in; (void)out_size;

    int NB = (N + 1023) / 1024;

    k_init<<<256, 256, 0, stream>>>(intdeg, cursor, accums, N);
    k_deg<<<1024, 256, 0, stream>>>(dstIdx, E, intdeg);
    k_dinv<<<(N + 255) / 256, 256, 0, stream>>>(intdeg, dinv, N);
    k_scan1<<<NB, 256, 0, stream>>>(intdeg, N, blockTotals);
    k_scan2<<<1, 64, 0, stream>>>(blockTotals, NB, blockOffs, offsets, N);
    k_scan3<<<NB, 256, 0, stream>>>(intdeg, N, blockOffs, offsets);
    k_fill<<<1024, 256, 0, stream>>>(srcIdx, dstIdx, E, offsets, cursor, dinv, csr_src, csr_w);
    k_pos<<<256, 256, 0, stream>>>(labels, N, accums);

    int gemmBlocks = (N + 31) / 32;
    int aggBlocks  = (N + 3) / 4;

    // conv1: 128 -> 100
    k_gemm<128><<<gemmBlocks, 256, 0, stream>>>(x, W1, nullptr, tbuf, N);
    k_agg<<<aggBlocks, 256, 0, stream>>>(tbuf, csr_src, csr_w, offsets, dinv, b1, hbuf, N);
    // conv2..9: 100 -> 100
    for (int i = 0; i < NHID; ++i) {
        k_gemm<100><<<gemmBlocks, 256, 0, stream>>>(hbuf, Wh + (size_t)i * HW * HW, nullptr, tbuf, N);
        k_agg<<<aggBlocks, 256, 0, stream>>>(tbuf, csr_src, csr_w, offsets, dinv, bh + (size_t)i * HW, hbuf, N);
    }
    // fc1 (+bias)
    k_gemm<100><<<gemmBlocks, 256, 0, stream>>>(hbuf, fc1W, fc1b, tbuf, N);
    // fc2 + sigmoid + loss
    float* outF = (float*)d_out;
    k_fc2_loss<<<(N + 3) / 4, 256, 0, stream>>>(tbuf, fc2W, fc2b, labels, accums,
                                                outF + 1, accums + 1, N);
    k_final<<<1, 64, 0, stream>>>(accums, outF, N);
}

// Round 2
// 393.114 us; speedup vs baseline: 6.7376x; 6.7376x over previous
//
#include <hip/hip_runtime.h>
#include <math.h>

#define HW 100
#define FIN 128
#define NHID 8

// ---------------- init ----------------
__global__ void k_init(int* __restrict__ intdeg, int* __restrict__ cursor,
                       float* __restrict__ accums, int n) {
    int i = blockIdx.x * blockDim.x + threadIdx.x;
    int st = gridDim.x * blockDim.x;
    for (; i < n; i += st) { intdeg[i] = 0; cursor[i] = 0; }
    if (blockIdx.x == 0 && threadIdx.x == 0) { accums[0] = 0.f; accums[1] = 0.f; }
}

// ---------------- degree count ----------------
__global__ void k_deg(const int* __restrict__ dst, int E, int* __restrict__ intdeg) {
    int i = blockIdx.x * blockDim.x + threadIdx.x;
    int st = gridDim.x * blockDim.x;
    for (; i < E; i += st) atomicAdd(&intdeg[dst[i]], 1);
}

// ---------------- dinv ----------------
__global__ void k_dinv(const int* __restrict__ intdeg, float* __restrict__ dinv, int n) {
    int i = blockIdx.x * blockDim.x + threadIdx.x;
    if (i < n) dinv[i] = rsqrtf((float)intdeg[i] + 1.0f);   // +1 self loop
}

// ---------------- 2-level exclusive scan of intdeg -> offsets ----------------
__global__ void k_scan1(const int* __restrict__ deg, int n, int* __restrict__ blockTotals) {
    __shared__ int s[256];
    int base = blockIdx.x * 1024 + threadIdx.x * 4;
    int tsum = 0;
    #pragma unroll
    for (int j = 0; j < 4; ++j) { int idx = base + j; tsum += (idx < n) ? deg[idx] : 0; }
    s[threadIdx.x] = tsum; __syncthreads();
    for (int off = 128; off; off >>= 1) {
        if (threadIdx.x < off) s[threadIdx.x] += s[threadIdx.x + off];
        __syncthreads();
    }
    if (threadIdx.x == 0) blockTotals[blockIdx.x] = s[0];
}

__global__ void k_scan2(const int* __restrict__ blockTotals, int nb,
                        int* __restrict__ blockOffsets, int* __restrict__ offsets, int n) {
    if (blockIdx.x == 0 && threadIdx.x == 0) {
        int run = 0;
        for (int i = 0; i < nb; ++i) { blockOffsets[i] = run; run += blockTotals[i]; }
        offsets[n] = run;
    }
}

__global__ void k_scan3(const int* __restrict__ deg, int n,
                        const int* __restrict__ blockOffsets, int* __restrict__ offsets) {
    __shared__ int s[256];
    int tid = threadIdx.x;
    int base = blockIdx.x * 1024 + tid * 4;
    int v[4]; int tsum = 0;
    #pragma unroll
    for (int j = 0; j < 4; ++j) { int idx = base + j; v[j] = (idx < n) ? deg[idx] : 0; tsum += v[j]; }
    s[tid] = tsum; __syncthreads();
    for (int off = 1; off < 256; off <<= 1) {
        int x = (tid >= off) ? s[tid - off] : 0;
        __syncthreads();
        s[tid] += x;
        __syncthreads();
    }
    int run = blockOffsets[blockIdx.x] + (s[tid] - tsum);
    #pragma unroll
    for (int j = 0; j < 4; ++j) { int idx = base + j; if (idx < n) offsets[idx] = run; run += v[j]; }
}

// ---------------- CSR fill ----------------
__global__ void k_fill(const int* __restrict__ src, const int* __restrict__ dst, int E,
                       const int* __restrict__ offsets, int* __restrict__ cursor,
                       const float* __restrict__ dinv,
                       int* __restrict__ csr_src, float* __restrict__ csr_w) {
    int i = blockIdx.x * blockDim.x + threadIdx.x;
    int st = gridDim.x * blockDim.x;
    for (; i < E; i += st) {
        int d = dst[i], s = src[i];
        int pos = offsets[d] + atomicAdd(&cursor[d], 1);
        csr_src[pos] = s;
        csr_w[pos] = dinv[s] * dinv[d];
    }
}

// ---------------- weight-chain collapse ----------------
// v-chain right-to-left; emit wstar[128] and gammas[1..9]
__global__ void k_chain(const float* __restrict__ W1, const float* __restrict__ b1,
                        const float* __restrict__ Wh, const float* __restrict__ bh,
                        const float* __restrict__ fc1W, const float* __restrict__ fc1b,
                        const float* __restrict__ fc2W, const float* __restrict__ fc2b,
                        float* __restrict__ wstar, float* __restrict__ gammas) {
    __shared__ float v[HW], vn[HW];
    int t = threadIdx.x;
    if (t < HW) v[t] = fc2W[t];
    __syncthreads();
    // v = fc1W @ v
    if (t < HW) { float a = 0.f; for (int c = 0; c < HW; ++c) a += fc1W[t * HW + c] * v[c]; vn[t] = a; }
    __syncthreads();
    if (t < HW) v[t] = vn[t];
    __syncthreads();
    if (t == 0) {
        float a = 0.f; for (int c = 0; c < HW; ++c) a += bh[7 * HW + c] * v[c];
        float b = 0.f; for (int c = 0; c < HW; ++c) b += fc1b[c] * fc2W[c];
        gammas[9] = a + b + fc2b[0];          // bias of layer 9 + fc const terms
    }
    __syncthreads();
    for (int i = 7; i >= 0; --i) {
        const float* M = Wh + (size_t)i * HW * HW;
        if (t < HW) { float a = 0.f; for (int c = 0; c < HW; ++c) a += M[t * HW + c] * v[c]; vn[t] = a; }
        __syncthreads();
        if (t < HW) v[t] = vn[t];
        __syncthreads();
        if (t == 0) {
            const float* bb = (i >= 1) ? (bh + (size_t)(i - 1) * HW) : b1;
            float a = 0.f; for (int c = 0; c < HW; ++c) a += bb[c] * v[c];
            gammas[i + 1] = a;
        }
        __syncthreads();
    }
    // wstar = W1 @ v (128 rows)
    { float a = 0.f; for (int c = 0; c < HW; ++c) a += W1[t * HW + c] * v[c]; wstar[t] = a; }
}

// ---------------- y = x @ wstar  (wave per row) ----------------
__global__ __launch_bounds__(256) void k_gemv(const float* __restrict__ x,
                                              const float* __restrict__ wstar,
                                              float* __restrict__ y, int n) {
    __shared__ float ws[FIN];
    int tid = threadIdx.x;
    if (tid < FIN) ws[tid] = wstar[tid];
    __syncthreads();
    int node = blockIdx.x * 4 + (tid >> 6);
    int lane = tid & 63;
    if (node >= n) return;
    const float* xr = x + (size_t)node * FIN;
    float2 a = *reinterpret_cast<const float2*>(&xr[lane * 2]);
    float v = a.x * ws[lane * 2] + a.y * ws[lane * 2 + 1];
    #pragma unroll
    for (int off = 32; off; off >>= 1) v += __shfl_down(v, off);
    if (lane == 0) y[node] = v;
}

// ---------------- scalar sparse apply: z = A y + gamma ----------------
__global__ __launch_bounds__(256) void k_apply(const float* __restrict__ y,
                                               const int* __restrict__ csr_src,
                                               const float* __restrict__ csr_w,
                                               const int* __restrict__ offsets,
                                               const float* __restrict__ dinv,
                                               const float* __restrict__ gammas, int k,
                                               float* __restrict__ z, int n) {
    int i = blockIdx.x * blockDim.x + threadIdx.x;
    if (i >= n) return;
    int beg = offsets[i], end = offsets[i + 1];
    float di = dinv[i];
    float acc = di * di * y[i];
    for (int e = beg; e < end; ++e)
        acc = fmaf(csr_w[e], y[csr_src[e]], acc);
    z[i] = acc + gammas[k];
}

// ---------------- pos = sum(labels) ----------------
__global__ void k_pos(const float* __restrict__ labels, int n, float* __restrict__ accums) {
    __shared__ float s[256];
    float v = 0.f;
    for (int i = blockIdx.x * blockDim.x + threadIdx.x; i < n; i += gridDim.x * blockDim.x)
        v += labels[i];
    s[threadIdx.x] = v; __syncthreads();
    for (int off = 128; off; off >>= 1) {
        if (threadIdx.x < off) s[threadIdx.x] += s[threadIdx.x + off];
        __syncthreads();
    }
    if (threadIdx.x == 0) atomicAdd(&accums[0], s[0]);
}

// ---------------- sigmoid + weighted BCE ----------------
__global__ __launch_bounds__(256) void k_loss(const float* __restrict__ L,
                                              const float* __restrict__ labels,
                                              const float* __restrict__ accums,
                                              float* __restrict__ out_p,
                                              float* __restrict__ loss_accum, int n) {
    __shared__ float s[256];
    float pos = accums[0];
    float wpos = ((float)n - pos) / pos;
    float acc = 0.f;
    for (int i = blockIdx.x * blockDim.x + threadIdx.x; i < n; i += gridDim.x * blockDim.x) {
        float logit = L[i];
        float p = 1.f / (1.f + expf(-logit));
        out_p[i] = p;
        float pc = fminf(fmaxf(p, 1e-7f), 1.f - 1e-7f);
        float l = labels[i];
        float w = wpos * l + 1.f;
        acc += w * (-(l * logf(pc) + (1.f - l) * logf(1.f - pc)));
    }
    s[threadIdx.x] = acc; __syncthreads();
    for (int off = 128; off; off >>= 1) {
        if (threadIdx.x < off) s[threadIdx.x] += s[threadIdx.x + off];
        __syncthreads();
    }
    if (threadIdx.x == 0) atomicAdd(loss_accum, s[0]);
}

__global__ void k_final(const float* __restrict__ accums, float* __restrict__ out0, int n) {
    if (blockIdx.x == 0 && threadIdx.x == 0) out0[0] = accums[1] / (float)n;
}

// ---------------- launch ----------------
extern "C" void kernel_launch(void* const* d_in, const int* in_sizes, int n_in,
                              void* d_out, int out_size, void* d_ws, size_t ws_size,
                              hipStream_t stream) {
    const float* x      = (const float*)d_in[0];
    const int*   edge   = (const int*)d_in[1];
    const float* labels = (const float*)d_in[2];
    const float* W1     = (const float*)d_in[3];
    const float* b1     = (const float*)d_in[4];
    const float* Wh     = (const float*)d_in[5];
    const float* bh     = (const float*)d_in[6];
    const float* fc1W   = (const float*)d_in[7];
    const float* fc1b   = (const float*)d_in[8];
    const float* fc2W   = (const float*)d_in[9];
    const float* fc2b   = (const float*)d_in[10];

    const int N = in_sizes[0] / FIN;   // 100000
    const int E = in_sizes[1] / 2;     // 1600000
    const int* srcIdx = edge;
    const int* dstIdx = edge + E;

    size_t o = 0;
    auto carve = [&](size_t bytes) {
        void* p = (char*)d_ws + o;
        o += (bytes + 511) & ~(size_t)511;
        return p;
    };
    float* dinv        = (float*)carve((size_t)N * 4);
    int*   offsets     = (int*)  carve((size_t)(N + 1) * 4);
    int*   intdeg      = (int*)  carve((size_t)N * 4);
    int*   cursor      = (int*)  carve((size_t)N * 4);
    int*   blockTotals = (int*)  carve(256 * 4);
    int*   blockOffs   = (int*)  carve(256 * 4);
    float* accums      = (float*)carve(2 * 4);
    float* wstar       = (float*)carve(FIN * 4);
    float* gammas      = (float*)carve(16 * 4);
    int*   csr_src     = (int*)  carve((size_t)E * 4);
    float* csr_w       = (float*)carve((size_t)E * 4);
    float* ybuf        = (float*)carve((size_t)N * 4);
    float* zbuf        = (float*)carve((size_t)N * 4);
    (void)ws_size; (void)n_in; (void)out_size;

    int NB = (N + 1023) / 1024;

    k_init<<<256, 256, 0, stream>>>(intdeg, cursor, accums, N);
    k_deg<<<1024, 256, 0, stream>>>(dstIdx, E, intdeg);
    k_dinv<<<(N + 255) / 256, 256, 0, stream>>>(intdeg, dinv, N);
    k_scan1<<<NB, 256, 0, stream>>>(intdeg, N, blockTotals);
    k_scan2<<<1, 64, 0, stream>>>(blockTotals, NB, blockOffs, offsets, N);
    k_scan3<<<NB, 256, 0, stream>>>(intdeg, N, blockOffs, offsets);
    k_fill<<<1024, 256, 0, stream>>>(srcIdx, dstIdx, E, offsets, cursor, dinv, csr_src, csr_w);
    k_pos<<<256, 256, 0, stream>>>(labels, N, accums);
    k_chain<<<1, FIN, 0, stream>>>(W1, b1, Wh, bh, fc1W, fc1b, fc2W, fc2b, wstar, gammas);

    // y = x @ wstar
    k_gemv<<<(N + 3) / 4, 256, 0, stream>>>(x, wstar, ybuf, N);

    // 9 scalar sparse applies with folded bias scalars
    float* ya = ybuf; float* yb = zbuf;
    for (int k = 1; k <= 9; ++k) {
        k_apply<<<(N + 255) / 256, 256, 0, stream>>>(ya, csr_src, csr_w, offsets, dinv,
                                                     gammas, k, yb, N);
        float* tmp = ya; ya = yb; yb = tmp;
    }

    float* outF = (float*)d_out;
    k_loss<<<512, 256, 0, stream>>>(ya, labels, accums, outF + 1, accums + 1, N);
    k_final<<<1, 64, 0, stream>>>(accums, outF, N);
}